// Round 1
// baseline (170.917 us; speedup 1.0000x reference)
//
#include <hip/hip_runtime.h>
#include <hip/hip_bf16.h>

typedef __attribute__((ext_vector_type(8))) short bf16x8;
typedef __attribute__((ext_vector_type(8))) unsigned short ushort8;
typedef __attribute__((ext_vector_type(4))) float f32x4;
typedef __attribute__((ext_vector_type(4))) unsigned int uint4v;

#define CIN_  128
#define BATCH 16
#define HW_   56
#define SP_   3136        // 56*56
#define CO_   256
#define NTILES 784        // 50176 / 64
// ws layout:
//   [0, 589824)        : Wt bf16 [9][256][128]  (ushort)
//   [589824, 594432)   : Wcnt float[1152]
//   [594432, 599040)   : Xcnt float[1152]

__device__ inline unsigned short f2bf(float f) {
    unsigned int u = __float_as_uint(f);
    u = (u + 0x7fffu + ((u >> 16) & 1u)) >> 16;   // round-to-nearest-even
    return (unsigned short)u;
}

// ---- weight transform: w[co][ci][kh][kw] f32 -> Wt[koff][co][ci] bf16 ----
__global__ void k_wt(const float* __restrict__ w, unsigned short* __restrict__ Wt) {
    int e = blockIdx.x * 256 + threadIdx.x;       // 294912 = 256*128*9
    float v = w[e];
    int co = e / 1152;
    int r  = e - co * 1152;
    int ci = r / 9;
    int koff = r - ci * 9;
    Wt[(koff * 256 + co) * 128 + ci] = f2bf(v);
}

// ---- Wcnt[ci*9+koff] = sum_co (w[co][ci][koff] != 0) ----
__global__ void k_wcnt(const float* __restrict__ w, float* __restrict__ Wcnt) {
    int j = blockIdx.x;                           // 1152
    int lane = threadIdx.x;                       // 64
    float c = 0.f;
    for (int co = lane; co < 256; co += 64)
        c += (w[(size_t)co * 1152 + j] != 0.0f) ? 1.f : 0.f;
    #pragma unroll
    for (int s = 32; s > 0; s >>= 1) c += __shfl_down(c, s, 64);
    if (lane == 0) Wcnt[j] = c;
}

// ---- Xcnt[ci*9+koff] = sum_b (nonzero count of x[b][ci] in koff's valid region) ----
__global__ void k_xcnt(const float* __restrict__ x, float* __restrict__ Xcnt) {
    int blk = blockIdx.x;                         // 2048 = b*128 + ci
    int ci = blk & 127;
    const float* xp = x + (size_t)blk * SP_;
    int tid = threadIdx.x;                        // 256
    float cnt[9];
    #pragma unroll
    for (int k = 0; k < 9; ++k) cnt[k] = 0.f;
    for (int e = tid; e < SP_; e += 256) {
        float v = xp[e];
        if (v != 0.f) {
            int h = e / 56, w_ = e - h * 56;
            float r0 = (h <= 54) ? 1.f : 0.f;     // kh=0 needs h<=54
            float r2 = (h >= 1) ? 1.f : 0.f;      // kh=2 needs h>=1
            float c0 = (w_ <= 54) ? 1.f : 0.f;
            float c2 = (w_ >= 1) ? 1.f : 0.f;
            cnt[0] += r0 * c0; cnt[1] += r0; cnt[2] += r0 * c2;
            cnt[3] += c0;      cnt[4] += 1.f; cnt[5] += c2;
            cnt[6] += r2 * c0; cnt[7] += r2; cnt[8] += r2 * c2;
        }
    }
    #pragma unroll
    for (int k = 0; k < 9; ++k) {
        #pragma unroll
        for (int s = 32; s > 0; s >>= 1) cnt[k] += __shfl_down(cnt[k], s, 64);
    }
    if ((tid & 63) == 0) {
        #pragma unroll
        for (int k = 0; k < 9; ++k)
            atomicAdd(&Xcnt[ci * 9 + k], cnt[k]);
    }
}

// ---- final sparsity scalar ----
__global__ void k_spars(const float* __restrict__ Wcnt, const float* __restrict__ Xcnt,
                        float* __restrict__ out_scalar) {
    __shared__ double red[256];
    int t = threadIdx.x;
    double s = 0.0;
    for (int j = t; j < 1152; j += 256)
        s += (double)Wcnt[j] * (double)Xcnt[j];
    red[t] = s; __syncthreads();
    for (int k = 128; k > 0; k >>= 1) {
        if (t < k) red[t] += red[t + k];
        __syncthreads();
    }
    if (t == 0) {
        const double ne = 14797504512.0;          // 16*56*56*256*128*9
        out_scalar[0] = (float)((ne - red[0]) / ne);
    }
}

// ---- main conv: implicit GEMM, 9 shifted K=128 GEMMs, bf16 MFMA ----
__global__ __launch_bounds__(256) void k_conv(
    const float* __restrict__ x, const unsigned short* __restrict__ Wt,
    const float* __restrict__ bias, float* __restrict__ out)
{
    __shared__ __attribute__((aligned(16))) unsigned short Alds[64][40]; // [co][ci] pad->80B rows
    __shared__ __attribute__((aligned(16))) unsigned short Blds[64][40]; // [n ][ci]

    const int tid  = threadIdx.x;
    const int lane = tid & 63;
    const int wid  = tid >> 6;
    const int wm   = wid >> 1, wn = wid & 1;

    const int n0  = blockIdx.x * 64;
    const int b   = blockIdx.x / 49;              // 3136/64 = 49 tiles per image
    const int sp0 = n0 - b * SP_;
    const int co0 = blockIdx.y * 64;

    // A staging: thread -> (co_l, 8 ci)
    const int a_co = tid >> 2;
    const int a_ci = (tid & 3) * 8;
    // B staging: thread -> (n_l, 8 ci)
    const int b_n  = tid & 63;
    const int b_k0 = (tid >> 6) * 8;

    const int sp = sp0 + b_n;
    const int oh = sp / 56, ow = sp - oh * 56;

    f32x4 acc[2][2] = {};
    const float* xb_base = x + (size_t)b * CIN_ * SP_;

    for (int koff = 0; koff < 9; ++koff) {
        const int dh = koff / 3 - 1, dw = koff - (koff / 3) * 3 - 1;
        const int ih = oh + dh, iw = ow + dw;
        const bool valid = ((unsigned)ih < 56u) && ((unsigned)iw < 56u);
        const float* xb = xb_base + sp + dh * 56 + dw;
        const unsigned short* wp = Wt + ((size_t)(koff * 256 + co0 + a_co)) * 128 + a_ci;

        for (int ci0 = 0; ci0 < 128; ci0 += 32) {
            // stage A (bf16 copy, 16B per thread)
            uint4v av = *(const uint4v*)(wp + ci0);
            *(uint4v*)&Alds[a_co][a_ci] = av;
            // stage B (f32 load + convert, 8 ci per thread)
            ushort8 bv;
            #pragma unroll
            for (int j = 0; j < 8; ++j) {
                int ci = ci0 + b_k0 + j;
                float v = 0.f;
                if (valid) v = xb[(size_t)ci * SP_];
                bv[j] = f2bf(v);
            }
            *(ushort8*)&Blds[b_n][b_k0] = bv;
            __syncthreads();

            const int row = lane & 15;
            const int kq  = (lane >> 4) * 8;
            bf16x8 a0 = *(const bf16x8*)&Alds[wm * 32 + row][kq];
            bf16x8 a1 = *(const bf16x8*)&Alds[wm * 32 + 16 + row][kq];
            bf16x8 bb0 = *(const bf16x8*)&Blds[wn * 32 + row][kq];
            bf16x8 bb1 = *(const bf16x8*)&Blds[wn * 32 + 16 + row][kq];
            acc[0][0] = __builtin_amdgcn_mfma_f32_16x16x32_bf16(a0, bb0, acc[0][0], 0, 0, 0);
            acc[0][1] = __builtin_amdgcn_mfma_f32_16x16x32_bf16(a0, bb1, acc[0][1], 0, 0, 0);
            acc[1][0] = __builtin_amdgcn_mfma_f32_16x16x32_bf16(a1, bb0, acc[1][0], 0, 0, 0);
            acc[1][1] = __builtin_amdgcn_mfma_f32_16x16x32_bf16(a1, bb1, acc[1][1], 0, 0, 0);
            __syncthreads();
        }
    }

    // epilogue: D row=(lane>>4)*4+r (co), col=lane&15 (n)
    const int col = lane & 15;
    const int rb  = (lane >> 4) * 4;
    #pragma unroll
    for (int f = 0; f < 2; ++f) {
        #pragma unroll
        for (int g = 0; g < 2; ++g) {
            int spc = sp0 + wn * 32 + g * 16 + col;
            #pragma unroll
            for (int r = 0; r < 4; ++r) {
                int co = co0 + wm * 32 + f * 16 + rb + r;
                out[((size_t)(b * CO_ + co)) * SP_ + spc] = acc[f][g][r] + bias[co];
            }
        }
    }
}

extern "C" void kernel_launch(void* const* d_in, const int* in_sizes, int n_in,
                              void* d_out, int out_size, void* d_ws, size_t ws_size,
                              hipStream_t stream) {
    const float* x    = (const float*)d_in[0];
    const float* w    = (const float*)d_in[1];
    const float* bias = (const float*)d_in[2];
    float* out = (float*)d_out;

    unsigned short* Wt = (unsigned short*)d_ws;
    float* Wcnt = (float*)((char*)d_ws + 589824);
    float* Xcnt = Wcnt + 1152;

    hipMemsetAsync((void*)Wcnt, 0, 2 * 1152 * sizeof(float), stream);
    hipLaunchKernelGGL(k_wt,    dim3(1152),   dim3(256), 0, stream, w, Wt);
    hipLaunchKernelGGL(k_wcnt,  dim3(1152),   dim3(64),  0, stream, w, Wcnt);
    hipLaunchKernelGGL(k_xcnt,  dim3(2048),   dim3(256), 0, stream, x, Xcnt);
    hipLaunchKernelGGL(k_conv,  dim3(NTILES, 4), dim3(256), 0, stream, x, Wt, bias, out);
    hipLaunchKernelGGL(k_spars, dim3(1),      dim3(256), 0, stream, Wcnt, Xcnt,
                       out + 12845056);
}

// Round 2
// 115.573 us; speedup vs baseline: 1.4789x; 1.4789x over previous
//
#include <hip/hip_runtime.h>
#include <hip/hip_bf16.h>

typedef __attribute__((ext_vector_type(8))) short bf16x8;
typedef __attribute__((ext_vector_type(8))) unsigned short ushort8;
typedef __attribute__((ext_vector_type(4))) unsigned short ushort4v;
typedef __attribute__((ext_vector_type(4))) float f32x4;
typedef __attribute__((ext_vector_type(4))) unsigned int uint4v;

#define CIN_  128
#define BATCH 16
#define SP_   3136        // 56*56
#define CO_   256
#define NTOT  50176       // BATCH*SP_

// ws layout (new path):
//   [0, 13778944)            : xp bf16 [16][58][58][128]  zero-padded halo
//   [13778944, 14368768)     : Wt bf16 [9][256][128]
//   [14368768, 14373376)     : Wcnt float[1152]
//   [14373376, 14377984)     : Xcnt float[1152]
#define XP_BYTES   13778944
#define WT_BYTES   589824
#define WS_NEEDED  14377984

__device__ __forceinline__ unsigned short f2bf(float f) {
    unsigned int u = __float_as_uint(f);
    u = (u + 0x7fffu + ((u >> 16) & 1u)) >> 16;   // RNE
    return (unsigned short)u;
}

__device__ __forceinline__ void gl_lds16(const unsigned short* g, unsigned short* l) {
    __builtin_amdgcn_global_load_lds(
        (const __attribute__((address_space(1))) unsigned int*)g,
        (__attribute__((address_space(3))) unsigned int*)l, 16, 0, 0);
}

// ---- weight transform: w[co][ci][kh][kw] f32 -> Wt[koff][co][ci] bf16 ----
__global__ void k_wt(const float* __restrict__ w, unsigned short* __restrict__ Wt) {
    int e = blockIdx.x * 256 + threadIdx.x;       // 294912
    float v = w[e];
    int co = e / 1152;
    int r  = e - co * 1152;
    int ci = r / 9;
    int koff = r - ci * 9;
    Wt[(koff * 256 + co) * 128 + ci] = f2bf(v);
}

// ---- Wcnt[j] = sum_co (w[co][j] != 0), j = ci*9+koff, coalesced ----
__global__ void k_wcnt(const float* __restrict__ w, float* __restrict__ Wcnt) {
    int j = blockIdx.x * 256 + threadIdx.x;
    if (j >= 1152) return;
    float c = 0.f;
    for (int co = 0; co < 256; ++co)
        c += (w[(size_t)co * 1152 + j] != 0.0f) ? 1.f : 0.f;
    Wcnt[j] = c;
}

// ---- Xcnt[ci*9+koff] = sum_b nonzero count of x[b][ci] in koff's valid region ----
__global__ void k_xcnt(const float* __restrict__ x, float* __restrict__ Xcnt) {
    int blk = blockIdx.x;                         // 2048 = b*128 + ci
    int ci = blk & 127;
    const float* xp = x + (size_t)blk * SP_;
    int tid = threadIdx.x;                        // 256
    float cnt[9];
    #pragma unroll
    for (int k = 0; k < 9; ++k) cnt[k] = 0.f;
    for (int e = tid; e < SP_; e += 256) {
        float v = xp[e];
        if (v != 0.f) {
            int h = e / 56, w_ = e - h * 56;
            float r0 = (h <= 54) ? 1.f : 0.f;
            float r2 = (h >= 1) ? 1.f : 0.f;
            float c0 = (w_ <= 54) ? 1.f : 0.f;
            float c2 = (w_ >= 1) ? 1.f : 0.f;
            cnt[0] += r0 * c0; cnt[1] += r0; cnt[2] += r0 * c2;
            cnt[3] += c0;      cnt[4] += 1.f; cnt[5] += c2;
            cnt[6] += r2 * c0; cnt[7] += r2; cnt[8] += r2 * c2;
        }
    }
    #pragma unroll
    for (int k = 0; k < 9; ++k) {
        #pragma unroll
        for (int s = 32; s > 0; s >>= 1) cnt[k] += __shfl_down(cnt[k], s, 64);
    }
    if ((tid & 63) == 0) {
        #pragma unroll
        for (int k = 0; k < 9; ++k)
            atomicAdd(&Xcnt[ci * 9 + k], cnt[k]);
    }
}

// ---- final sparsity scalar ----
__global__ void k_spars(const float* __restrict__ Wcnt, const float* __restrict__ Xcnt,
                        float* __restrict__ out_scalar) {
    __shared__ double red[256];
    int t = threadIdx.x;
    double s = 0.0;
    for (int j = t; j < 1152; j += 256)
        s += (double)Wcnt[j] * (double)Xcnt[j];
    red[t] = s; __syncthreads();
    for (int k = 128; k > 0; k >>= 1) {
        if (t < k) red[t] += red[t + k];
        __syncthreads();
    }
    if (t == 0) {
        const double ne = 14797504512.0;
        out_scalar[0] = (float)((ne - red[0]) / ne);
    }
}

// ---- x transpose + pad + bf16: x[b][ci][sp] f32 -> xp[b][ih][iw][ci] bf16 ----
__global__ __launch_bounds__(256) void k_xt(const float* __restrict__ x,
                                            unsigned short* __restrict__ xp) {
    __shared__ float T[64][65];
    const int tid = threadIdx.x;
    const int sp0 = blockIdx.x * 64;
    const int ci0 = blockIdx.y * 64;
    const int b   = blockIdx.z;
    const float* xb = x + ((size_t)(b * 128 + ci0)) * SP_ + sp0;
    #pragma unroll
    for (int r = 0; r < 16; ++r) {
        const int ci_l = (tid >> 6) * 16 + r;
        const int sp_l = tid & 63;
        T[sp_l][ci_l] = xb[(size_t)ci_l * SP_ + sp_l];
    }
    __syncthreads();
    #pragma unroll
    for (int r = 0; r < 4; ++r) {
        const int sp_l = (tid >> 4) * 4 + r;
        const int cc   = (tid & 15) * 4;
        const int sp = sp0 + sp_l;
        const int oh = sp / 56, ow = sp - oh * 56;
        ushort4v v;
        #pragma unroll
        for (int j = 0; j < 4; ++j) v[j] = f2bf(T[sp_l][cc + j]);
        *(ushort4v*)&xp[(((size_t)b * 58 + oh + 1) * 58 + (ow + 1)) * 128 + ci0 + cc] = v;
    }
}

// ---- main conv: implicit GEMM 128x128 tile, BK=64, global_load_lds + XOR swizzle ----
__global__ __launch_bounds__(256) void k_conv2(
    const unsigned short* __restrict__ xp, const unsigned short* __restrict__ Wt,
    const float* __restrict__ bias, float* __restrict__ out)
{
    __shared__ __attribute__((aligned(16))) unsigned short Alds[128 * 64]; // 16 KB
    __shared__ __attribute__((aligned(16))) unsigned short Blds[128 * 64]; // 16 KB

    const int tid  = threadIdx.x;
    const int lane = tid & 63;
    const int w    = tid >> 6;
    const int wm   = w >> 1, wn = w & 1;

    const int n0  = blockIdx.x * 128;
    const int co0 = blockIdx.y * 128;

    // staging maps: call q stages 16B chunk g=(w*4+q)*64+lane -> row=g>>3, phys p=g&7
    // source supplies logical chunk c = p ^ (row&7)  (rule-21 involution)
    int aoff[4], boff[4];
    #pragma unroll
    for (int q = 0; q < 4; ++q) {
        int g   = (w * 4 + q) * 64 + lane;
        int row = g >> 3;
        int c   = (g & 7) ^ (row & 7);
        aoff[q] = (co0 + row) * 128 + c * 8;
        int n  = n0 + row;
        int b  = n / SP_;
        int sp = n - b * SP_;
        int oh = sp / 56, ow = sp - oh * 56;
        boff[q] = ((b * 58 + oh + 1) * 58 + (ow + 1)) * 128 + c * 8;
    }

    f32x4 acc[4][4] = {};

    const int l15 = lane & 15;
    const int pc0 = (lane >> 4) ^ (lane & 7);
    const int pc1 = ((lane >> 4) + 4) ^ (lane & 7);
    const unsigned short* Abase = &Alds[(wm * 64 + l15) * 64];
    const unsigned short* Bbase = &Blds[(wn * 64 + l15) * 64];

    for (int koff = 0; koff < 9; ++koff) {
        const int dh = koff / 3 - 1, dw = koff - (koff / 3) * 3 - 1;
        const int bshk = (dh * 58 + dw) * 128;
        const int ashk = koff * 32768;            // 256*128
        #pragma unroll
        for (int half = 0; half < 2; ++half) {
            const int ci0 = half * 64;
            const int ash = ashk + ci0;
            const int bsh = bshk + ci0;
            #pragma unroll
            for (int q = 0; q < 4; ++q) {
                gl_lds16(Wt + ash + aoff[q], &Alds[(w * 4 + q) * 512]);
                gl_lds16(xp + bsh + boff[q], &Blds[(w * 4 + q) * 512]);
            }
            __syncthreads();

            bf16x8 a0[4], b0[4];
            #pragma unroll
            for (int m = 0; m < 4; ++m) a0[m] = *(const bf16x8*)(Abase + m * 1024 + pc0 * 8);
            #pragma unroll
            for (int n = 0; n < 4; ++n) b0[n] = *(const bf16x8*)(Bbase + n * 1024 + pc0 * 8);
            #pragma unroll
            for (int m = 0; m < 4; ++m)
                #pragma unroll
                for (int n = 0; n < 4; ++n)
                    acc[m][n] = __builtin_amdgcn_mfma_f32_16x16x32_bf16(a0[m], b0[n], acc[m][n], 0, 0, 0);

            bf16x8 a1[4], b1[4];
            #pragma unroll
            for (int m = 0; m < 4; ++m) a1[m] = *(const bf16x8*)(Abase + m * 1024 + pc1 * 8);
            #pragma unroll
            for (int n = 0; n < 4; ++n) b1[n] = *(const bf16x8*)(Bbase + n * 1024 + pc1 * 8);
            #pragma unroll
            for (int m = 0; m < 4; ++m)
                #pragma unroll
                for (int n = 0; n < 4; ++n)
                    acc[m][n] = __builtin_amdgcn_mfma_f32_16x16x32_bf16(a1[m], b1[n], acc[m][n], 0, 0, 0);

            __syncthreads();
        }
    }

    // epilogue: D col(n)=lane&15, row(co)=(lane>>4)*4+r
    const int rb = (lane >> 4) * 4;
    #pragma unroll
    for (int nf = 0; nf < 4; ++nf) {
        int n  = n0 + wn * 64 + nf * 16 + l15;
        int b  = n / SP_;
        int sp = n - b * SP_;
        float* op = out + (size_t)b * CO_ * SP_ + sp;
        #pragma unroll
        for (int m = 0; m < 4; ++m) {
            int co = co0 + wm * 64 + m * 16 + rb;
            #pragma unroll
            for (int r = 0; r < 4; ++r)
                op[(size_t)(co + r) * SP_] = acc[m][nf][r] + bias[co + r];
        }
    }
}

// ---- fallback (R1 kernel) if ws too small ----
__global__ __launch_bounds__(256) void k_conv(
    const float* __restrict__ x, const unsigned short* __restrict__ Wt,
    const float* __restrict__ bias, float* __restrict__ out)
{
    __shared__ __attribute__((aligned(16))) unsigned short AldsF[64][40];
    __shared__ __attribute__((aligned(16))) unsigned short BldsF[64][40];

    const int tid  = threadIdx.x;
    const int lane = tid & 63;
    const int wid  = tid >> 6;
    const int wm   = wid >> 1, wn = wid & 1;

    const int n0  = blockIdx.x * 64;
    const int b   = blockIdx.x / 49;
    const int sp0 = n0 - b * SP_;
    const int co0 = blockIdx.y * 64;

    const int a_co = tid >> 2;
    const int a_ci = (tid & 3) * 8;
    const int b_n  = tid & 63;
    const int b_k0 = (tid >> 6) * 8;

    const int sp = sp0 + b_n;
    const int oh = sp / 56, ow = sp - oh * 56;

    f32x4 acc[2][2] = {};
    const float* xb_base = x + (size_t)b * CIN_ * SP_;

    for (int koff = 0; koff < 9; ++koff) {
        const int dh = koff / 3 - 1, dw = koff - (koff / 3) * 3 - 1;
        const int ih = oh + dh, iw = ow + dw;
        const bool valid = ((unsigned)ih < 56u) && ((unsigned)iw < 56u);
        const float* xb = xb_base + sp + dh * 56 + dw;
        const unsigned short* wp = Wt + ((size_t)(koff * 256 + co0 + a_co)) * 128 + a_ci;

        for (int ci0 = 0; ci0 < 128; ci0 += 32) {
            uint4v av = *(const uint4v*)(wp + ci0);
            *(uint4v*)&AldsF[a_co][a_ci] = av;
            ushort8 bv;
            #pragma unroll
            for (int j = 0; j < 8; ++j) {
                int ci = ci0 + b_k0 + j;
                float v = 0.f;
                if (valid) v = xb[(size_t)ci * SP_];
                bv[j] = f2bf(v);
            }
            *(ushort8*)&BldsF[b_n][b_k0] = bv;
            __syncthreads();

            const int row = lane & 15;
            const int kq  = (lane >> 4) * 8;
            bf16x8 a0 = *(const bf16x8*)&AldsF[wm * 32 + row][kq];
            bf16x8 a1 = *(const bf16x8*)&AldsF[wm * 32 + 16 + row][kq];
            bf16x8 bb0 = *(const bf16x8*)&BldsF[wn * 32 + row][kq];
            bf16x8 bb1 = *(const bf16x8*)&BldsF[wn * 32 + 16 + row][kq];
            acc[0][0] = __builtin_amdgcn_mfma_f32_16x16x32_bf16(a0, bb0, acc[0][0], 0, 0, 0);
            acc[0][1] = __builtin_amdgcn_mfma_f32_16x16x32_bf16(a0, bb1, acc[0][1], 0, 0, 0);
            acc[1][0] = __builtin_amdgcn_mfma_f32_16x16x32_bf16(a1, bb0, acc[1][0], 0, 0, 0);
            acc[1][1] = __builtin_amdgcn_mfma_f32_16x16x32_bf16(a1, bb1, acc[1][1], 0, 0, 0);
            __syncthreads();
        }
    }

    const int col = lane & 15;
    const int rb  = (lane >> 4) * 4;
    #pragma unroll
    for (int f = 0; f < 2; ++f) {
        #pragma unroll
        for (int g = 0; g < 2; ++g) {
            int spc = sp0 + wn * 32 + g * 16 + col;
            #pragma unroll
            for (int r = 0; r < 4; ++r) {
                int co = co0 + wm * 32 + f * 16 + rb + r;
                out[((size_t)(b * CO_ + co)) * SP_ + spc] = acc[f][g][r] + bias[co];
            }
        }
    }
}

extern "C" void kernel_launch(void* const* d_in, const int* in_sizes, int n_in,
                              void* d_out, int out_size, void* d_ws, size_t ws_size,
                              hipStream_t stream) {
    const float* x    = (const float*)d_in[0];
    const float* w    = (const float*)d_in[1];
    const float* bias = (const float*)d_in[2];
    float* out = (float*)d_out;

    if (ws_size >= (size_t)WS_NEEDED) {
        unsigned short* xp = (unsigned short*)d_ws;
        unsigned short* Wt = (unsigned short*)((char*)d_ws + XP_BYTES);
        float* Wcnt = (float*)((char*)d_ws + XP_BYTES + WT_BYTES);
        float* Xcnt = Wcnt + 1152;

        hipMemsetAsync((void*)xp, 0, XP_BYTES, stream);
        hipMemsetAsync((void*)Wcnt, 0, 2 * 1152 * sizeof(float), stream);
        hipLaunchKernelGGL(k_wt,    dim3(1152),        dim3(256), 0, stream, w, Wt);
        hipLaunchKernelGGL(k_wcnt,  dim3(5),           dim3(256), 0, stream, w, Wcnt);
        hipLaunchKernelGGL(k_xcnt,  dim3(2048),        dim3(256), 0, stream, x, Xcnt);
        hipLaunchKernelGGL(k_xt,    dim3(49, 2, 16),   dim3(256), 0, stream, x, xp);
        hipLaunchKernelGGL(k_conv2, dim3(392, 2),      dim3(256), 0, stream, xp, Wt, bias, out);
        hipLaunchKernelGGL(k_spars, dim3(1),           dim3(256), 0, stream, Wcnt, Xcnt,
                           out + 12845056);
    } else {
        unsigned short* Wt = (unsigned short*)d_ws;
        float* Wcnt = (float*)((char*)d_ws + WT_BYTES);
        float* Xcnt = Wcnt + 1152;

        hipMemsetAsync((void*)Wcnt, 0, 2 * 1152 * sizeof(float), stream);
        hipLaunchKernelGGL(k_wt,    dim3(1152),      dim3(256), 0, stream, w, Wt);
        hipLaunchKernelGGL(k_wcnt,  dim3(5),         dim3(256), 0, stream, w, Wcnt);
        hipLaunchKernelGGL(k_xcnt,  dim3(2048),      dim3(256), 0, stream, x, Xcnt);
        hipLaunchKernelGGL(k_conv,  dim3(784, 4),    dim3(256), 0, stream, x, Wt, bias, out);
        hipLaunchKernelGGL(k_spars, dim3(1),         dim3(256), 0, stream, Wcnt, Xcnt,
                           out + 12845056);
    }
}

// Round 3
// 115.221 us; speedup vs baseline: 1.4834x; 1.0031x over previous
//
#include <hip/hip_runtime.h>
#include <hip/hip_bf16.h>

typedef __attribute__((ext_vector_type(8))) short bf16x8;
typedef __attribute__((ext_vector_type(8))) unsigned short ushort8;
typedef __attribute__((ext_vector_type(4))) unsigned short ushort4v;
typedef __attribute__((ext_vector_type(4))) float f32x4;
typedef __attribute__((ext_vector_type(4))) unsigned int uint4v;

#define CIN_  128
#define BATCH 16
#define SP_   3136        // 56*56
#define CO_   256
#define NTOT  50176       // BATCH*SP_

// ws layout:
//   [0, 13778944)            : xp bf16 [16][58][58][128]  zero-padded halo
//   [13778944, 14368768)     : Wt bf16 [9][256][128]
//   [14368768, 14373376)     : Wcnt float[1152]
//   [14373376, 14377984)     : Xcnt float[1152]
#define XP_BYTES   13778944
#define WT_BYTES   589824
#define WS_NEEDED  14377984

__device__ __forceinline__ unsigned short f2bf(float f) {
    unsigned int u = __float_as_uint(f);
    u = (u + 0x7fffu + ((u >> 16) & 1u)) >> 16;   // RNE
    return (unsigned short)u;
}

__device__ __forceinline__ void gl_lds16(const unsigned short* g, unsigned short* l) {
    __builtin_amdgcn_global_load_lds(
        (const __attribute__((address_space(1))) unsigned int*)g,
        (__attribute__((address_space(3))) unsigned int*)l, 16, 0, 0);
}

// ---- weight transform: w[co][ci][kh][kw] f32 -> Wt[koff][co][ci] bf16 ----
__global__ void k_wt(const float* __restrict__ w, unsigned short* __restrict__ Wt) {
    int e = blockIdx.x * 256 + threadIdx.x;       // 294912
    float v = w[e];
    int co = e / 1152;
    int r  = e - co * 1152;
    int ci = r / 9;
    int koff = r - ci * 9;
    Wt[(koff * 256 + co) * 128 + ci] = f2bf(v);
}

// ---- Wcnt[j] = sum_co (w[co][j] != 0)  — 1152 blocks, latency hidden by block count ----
__global__ void k_wcnt(const float* __restrict__ w, float* __restrict__ Wcnt) {
    int j = blockIdx.x;                           // 1152
    int lane = threadIdx.x;                       // 64
    float c = 0.f;
    for (int co = lane; co < 256; co += 64)
        c += (w[(size_t)co * 1152 + j] != 0.0f) ? 1.f : 0.f;
    #pragma unroll
    for (int s = 32; s > 0; s >>= 1) c += __shfl_down(c, s, 64);
    if (lane == 0) Wcnt[j] = c;
}

// ---- Xcnt[ci*9+koff] = sum_b nonzero count of x[b][ci] in koff's valid region ----
__global__ void k_xcnt(const float* __restrict__ x, float* __restrict__ Xcnt) {
    int blk = blockIdx.x;                         // 2048 = b*128 + ci
    int ci = blk & 127;
    const float* xp = x + (size_t)blk * SP_;
    int tid = threadIdx.x;                        // 256
    float cnt[9];
    #pragma unroll
    for (int k = 0; k < 9; ++k) cnt[k] = 0.f;
    for (int e = tid; e < SP_; e += 256) {
        float v = xp[e];
        if (v != 0.f) {
            int h = e / 56, w_ = e - h * 56;
            float r0 = (h <= 54) ? 1.f : 0.f;
            float r2 = (h >= 1) ? 1.f : 0.f;
            float c0 = (w_ <= 54) ? 1.f : 0.f;
            float c2 = (w_ >= 1) ? 1.f : 0.f;
            cnt[0] += r0 * c0; cnt[1] += r0; cnt[2] += r0 * c2;
            cnt[3] += c0;      cnt[4] += 1.f; cnt[5] += c2;
            cnt[6] += r2 * c0; cnt[7] += r2; cnt[8] += r2 * c2;
        }
    }
    #pragma unroll
    for (int k = 0; k < 9; ++k) {
        #pragma unroll
        for (int s = 32; s > 0; s >>= 1) cnt[k] += __shfl_down(cnt[k], s, 64);
    }
    if ((tid & 63) == 0) {
        #pragma unroll
        for (int k = 0; k < 9; ++k)
            atomicAdd(&Xcnt[ci * 9 + k], cnt[k]);
    }
}

// ---- final sparsity scalar ----
__global__ void k_spars(const float* __restrict__ Wcnt, const float* __restrict__ Xcnt,
                        float* __restrict__ out_scalar) {
    __shared__ double red[256];
    int t = threadIdx.x;
    double s = 0.0;
    for (int j = t; j < 1152; j += 256)
        s += (double)Wcnt[j] * (double)Xcnt[j];
    red[t] = s; __syncthreads();
    for (int k = 128; k > 0; k >>= 1) {
        if (t < k) red[t] += red[t + k];
        __syncthreads();
    }
    if (t == 0) {
        const double ne = 14797504512.0;
        out_scalar[0] = (float)((ne - red[0]) / ne);
    }
}

// ---- x transpose + pad + bf16: x[b][ci][sp] f32 -> xp[b][ih][iw][ci] bf16 ----
__global__ __launch_bounds__(256) void k_xt(const float* __restrict__ x,
                                            unsigned short* __restrict__ xp) {
    __shared__ float T[64][65];
    const int tid = threadIdx.x;
    const int sp0 = blockIdx.x * 64;
    const int ci0 = blockIdx.y * 64;
    const int b   = blockIdx.z;
    const float* xb = x + ((size_t)(b * 128 + ci0)) * SP_ + sp0;
    #pragma unroll
    for (int r = 0; r < 16; ++r) {
        const int ci_l = (tid >> 6) * 16 + r;
        const int sp_l = tid & 63;
        T[sp_l][ci_l] = xb[(size_t)ci_l * SP_ + sp_l];
    }
    __syncthreads();
    #pragma unroll
    for (int r = 0; r < 4; ++r) {
        const int sp_l = (tid >> 4) * 4 + r;
        const int cc   = (tid & 15) * 4;
        const int sp = sp0 + sp_l;
        const int oh = sp / 56, ow = sp - oh * 56;
        ushort4v v;
        #pragma unroll
        for (int j = 0; j < 4; ++j) v[j] = f2bf(T[sp_l][cc + j]);
        *(ushort4v*)&xp[(((size_t)b * 58 + oh + 1) * 58 + (ow + 1)) * 128 + ci0 + cc] = v;
    }
}

// ---- main conv: implicit GEMM 128x128, BK=64, 2-phase double-buffered pipeline ----
__global__ __launch_bounds__(256) void k_conv2(
    const unsigned short* __restrict__ xp, const unsigned short* __restrict__ Wt,
    const float* __restrict__ bias, float* __restrict__ out)
{
    __shared__ __attribute__((aligned(16))) unsigned short Alds[2 * 8192]; // 32 KB
    __shared__ __attribute__((aligned(16))) unsigned short Blds[2 * 8192]; // 32 KB

    const int tid  = threadIdx.x;
    const int lane = tid & 63;
    const int w    = tid >> 6;
    const int wm   = w >> 1, wn = w & 1;

    const int n0  = blockIdx.x * 128;
    const int co0 = blockIdx.y * 128;

    // staging maps: call q stages 16B chunk g=(w*4+q)*64+lane -> row=g>>3, phys p=g&7
    // source supplies logical chunk c = p ^ (row&7)  (rule-21 involution)
    int aoff[4], boff[4];
    #pragma unroll
    for (int q = 0; q < 4; ++q) {
        int g   = (w * 4 + q) * 64 + lane;
        int row = g >> 3;
        int c   = (g & 7) ^ (row & 7);
        aoff[q] = (co0 + row) * 128 + c * 8;
        int n  = n0 + row;
        int b  = n / SP_;
        int sp = n - b * SP_;
        int oh = sp / 56, ow = sp - oh * 56;
        boff[q] = ((b * 58 + oh + 1) * 58 + (ow + 1)) * 128 + c * 8;
    }

    f32x4 acc[4][4] = {};

    const int l15 = lane & 15;
    const int pc0 = (lane >> 4) ^ (lane & 7);
    const int pc1 = ((lane >> 4) + 4) ^ (lane & 7);

    // stage step t (t = koff*2 + half) into buffer `buf`
    auto stage = [&](int t, int buf) {
        int koff = t >> 1, half = t & 1;
        int kd   = koff / 3;
        int dh   = kd - 1, dw = koff - kd * 3 - 1;
        int ash  = koff * 32768 + half * 64;
        int bsh  = (dh * 58 + dw) * 128 + half * 64;
        #pragma unroll
        for (int q = 0; q < 4; ++q) {
            gl_lds16(Wt + ash + aoff[q], &Alds[buf * 8192 + (w * 4 + q) * 512]);
            gl_lds16(xp + bsh + boff[q], &Blds[buf * 8192 + (w * 4 + q) * 512]);
        }
    };

    stage(0, 0);
    __syncthreads();                               // drains vmcnt(0)

    for (int t = 0; t < 18; ++t) {
        const int cur = t & 1;
        if (t < 17) stage(t + 1, cur ^ 1);         // prefetch next step

        const unsigned short* Abase = Alds + cur * 8192 + (wm * 64 + l15) * 64;
        const unsigned short* Bbase = Blds + cur * 8192 + (wn * 64 + l15) * 64;

        bf16x8 a0[4], b0[4];
        #pragma unroll
        for (int m = 0; m < 4; ++m) a0[m] = *(const bf16x8*)(Abase + m * 1024 + pc0 * 8);
        #pragma unroll
        for (int n = 0; n < 4; ++n) b0[n] = *(const bf16x8*)(Bbase + n * 1024 + pc0 * 8);
        #pragma unroll
        for (int m = 0; m < 4; ++m)
            #pragma unroll
            for (int n = 0; n < 4; ++n)
                acc[m][n] = __builtin_amdgcn_mfma_f32_16x16x32_bf16(a0[m], b0[n], acc[m][n], 0, 0, 0);

        bf16x8 a1[4], b1[4];
        #pragma unroll
        for (int m = 0; m < 4; ++m) a1[m] = *(const bf16x8*)(Abase + m * 1024 + pc1 * 8);
        #pragma unroll
        for (int n = 0; n < 4; ++n) b1[n] = *(const bf16x8*)(Bbase + n * 1024 + pc1 * 8);
        #pragma unroll
        for (int m = 0; m < 4; ++m)
            #pragma unroll
            for (int n = 0; n < 4; ++n)
                acc[m][n] = __builtin_amdgcn_mfma_f32_16x16x32_bf16(a1[m], b1[n], acc[m][n], 0, 0, 0);

        __syncthreads();                           // drains vmcnt(0): next buf ready
    }

    // epilogue: D col(n)=lane&15, row(co)=(lane>>4)*4+r
    const int rb = (lane >> 4) * 4;
    #pragma unroll
    for (int nf = 0; nf < 4; ++nf) {
        int n  = n0 + wn * 64 + nf * 16 + l15;
        int b  = n / SP_;
        int sp = n - b * SP_;
        float* op = out + (size_t)b * CO_ * SP_ + sp;
        #pragma unroll
        for (int m = 0; m < 4; ++m) {
            int co = co0 + wm * 64 + m * 16 + rb;
            #pragma unroll
            for (int r = 0; r < 4; ++r)
                op[(size_t)(co + r) * SP_] = acc[m][nf][r] + bias[co + r];
        }
    }
}

// ---- fallback (R1 kernel) if ws too small ----
__global__ __launch_bounds__(256) void k_conv(
    const float* __restrict__ x, const unsigned short* __restrict__ Wt,
    const float* __restrict__ bias, float* __restrict__ out)
{
    __shared__ __attribute__((aligned(16))) unsigned short AldsF[64][40];
    __shared__ __attribute__((aligned(16))) unsigned short BldsF[64][40];

    const int tid  = threadIdx.x;
    const int lane = tid & 63;
    const int wid  = tid >> 6;
    const int wm   = wid >> 1, wn = wid & 1;

    const int n0  = blockIdx.x * 64;
    const int b   = blockIdx.x / 49;
    const int sp0 = n0 - b * SP_;
    const int co0 = blockIdx.y * 64;

    const int a_co = tid >> 2;
    const int a_ci = (tid & 3) * 8;
    const int b_n  = tid & 63;
    const int b_k0 = (tid >> 6) * 8;

    const int sp = sp0 + b_n;
    const int oh = sp / 56, ow = sp - oh * 56;

    f32x4 acc[2][2] = {};
    const float* xb_base = x + (size_t)b * CIN_ * SP_;

    for (int koff = 0; koff < 9; ++koff) {
        const int dh = koff / 3 - 1, dw = koff - (koff / 3) * 3 - 1;
        const int ih = oh + dh, iw = ow + dw;
        const bool valid = ((unsigned)ih < 56u) && ((unsigned)iw < 56u);
        const float* xb = xb_base + sp + dh * 56 + dw;
        const unsigned short* wp = Wt + ((size_t)(koff * 256 + co0 + a_co)) * 128 + a_ci;

        for (int ci0 = 0; ci0 < 128; ci0 += 32) {
            uint4v av = *(const uint4v*)(wp + ci0);
            *(uint4v*)&AldsF[a_co][a_ci] = av;
            ushort8 bv;
            #pragma unroll
            for (int j = 0; j < 8; ++j) {
                int ci = ci0 + b_k0 + j;
                float v = 0.f;
                if (valid) v = xb[(size_t)ci * SP_];
                bv[j] = f2bf(v);
            }
            *(ushort8*)&BldsF[b_n][b_k0] = bv;
            __syncthreads();

            const int row = lane & 15;
            const int kq  = (lane >> 4) * 8;
            bf16x8 a0 = *(const bf16x8*)&AldsF[wm * 32 + row][kq];
            bf16x8 a1 = *(const bf16x8*)&AldsF[wm * 32 + 16 + row][kq];
            bf16x8 bb0 = *(const bf16x8*)&BldsF[wn * 32 + row][kq];
            bf16x8 bb1 = *(const bf16x8*)&BldsF[wn * 32 + 16 + row][kq];
            acc[0][0] = __builtin_amdgcn_mfma_f32_16x16x32_bf16(a0, bb0, acc[0][0], 0, 0, 0);
            acc[0][1] = __builtin_amdgcn_mfma_f32_16x16x32_bf16(a0, bb1, acc[0][1], 0, 0, 0);
            acc[1][0] = __builtin_amdgcn_mfma_f32_16x16x32_bf16(a1, bb0, acc[1][0], 0, 0, 0);
            acc[1][1] = __builtin_amdgcn_mfma_f32_16x16x32_bf16(a1, bb1, acc[1][1], 0, 0, 0);
            __syncthreads();
        }
    }

    const int col = lane & 15;
    const int rb  = (lane >> 4) * 4;
    #pragma unroll
    for (int f = 0; f < 2; ++f) {
        #pragma unroll
        for (int g = 0; g < 2; ++g) {
            int spc = sp0 + wn * 32 + g * 16 + col;
            #pragma unroll
            for (int r = 0; r < 4; ++r) {
                int co = co0 + wm * 32 + f * 16 + rb + r;
                out[((size_t)(b * CO_ + co)) * SP_ + spc] = acc[f][g][r] + bias[co];
            }
        }
    }
}

extern "C" void kernel_launch(void* const* d_in, const int* in_sizes, int n_in,
                              void* d_out, int out_size, void* d_ws, size_t ws_size,
                              hipStream_t stream) {
    const float* x    = (const float*)d_in[0];
    const float* w    = (const float*)d_in[1];
    const float* bias = (const float*)d_in[2];
    float* out = (float*)d_out;

    if (ws_size >= (size_t)WS_NEEDED) {
        unsigned short* xp = (unsigned short*)d_ws;
        unsigned short* Wt = (unsigned short*)((char*)d_ws + XP_BYTES);
        float* Wcnt = (float*)((char*)d_ws + XP_BYTES + WT_BYTES);
        float* Xcnt = Wcnt + 1152;

        hipMemsetAsync((void*)xp, 0, XP_BYTES, stream);
        hipMemsetAsync((void*)Xcnt, 0, 1152 * sizeof(float), stream);
        hipLaunchKernelGGL(k_wt,    dim3(1152),        dim3(256), 0, stream, w, Wt);
        hipLaunchKernelGGL(k_wcnt,  dim3(1152),        dim3(64),  0, stream, w, Wcnt);
        hipLaunchKernelGGL(k_xcnt,  dim3(2048),        dim3(256), 0, stream, x, Xcnt);
        hipLaunchKernelGGL(k_xt,    dim3(49, 2, 16),   dim3(256), 0, stream, x, xp);
        hipLaunchKernelGGL(k_conv2, dim3(392, 2),      dim3(256), 0, stream, xp, Wt, bias, out);
        hipLaunchKernelGGL(k_spars, dim3(1),           dim3(256), 0, stream, Wcnt, Xcnt,
                           out + 12845056);
    } else {
        unsigned short* Wt = (unsigned short*)d_ws;
        float* Wcnt = (float*)((char*)d_ws + WT_BYTES);
        float* Xcnt = Wcnt + 1152;

        hipMemsetAsync((void*)Xcnt, 0, 1152 * sizeof(float), stream);
        hipLaunchKernelGGL(k_wt,    dim3(1152),      dim3(256), 0, stream, w, Wt);
        hipLaunchKernelGGL(k_wcnt,  dim3(1152),      dim3(64),  0, stream, w, Wcnt);
        hipLaunchKernelGGL(k_xcnt,  dim3(2048),      dim3(256), 0, stream, x, Xcnt);
        hipLaunchKernelGGL(k_conv,  dim3(784, 4),    dim3(256), 0, stream, x, Wt, bias, out);
        hipLaunchKernelGGL(k_spars, dim3(1),         dim3(256), 0, stream, Wcnt, Xcnt,
                           out + 12845056);
    }
}

// Round 4
// 108.366 us; speedup vs baseline: 1.5772x; 1.0633x over previous
//
#include <hip/hip_runtime.h>
#include <hip/hip_bf16.h>

typedef __attribute__((ext_vector_type(8))) short bf16x8;
typedef __attribute__((ext_vector_type(8))) unsigned short ushort8;
typedef __attribute__((ext_vector_type(4))) unsigned short ushort4v;
typedef __attribute__((ext_vector_type(4))) float f32x4;
typedef __attribute__((ext_vector_type(4))) unsigned int uint4v;

#define CIN_  128
#define BATCH 16
#define SP_   3136        // 56*56
#define CO_   256
#define NTOT  50176       // BATCH*SP_

// ws layout:
//   [0, 13778944)            : xp bf16 [16][58][58][128]  zero-padded halo
//   [13778944, 14368768)     : Wt bf16 [9][256][128]
//   [14368768, 14373376)     : Wcnt float[1152]
//   [14373376, 14377984)     : Xcnt float[1152]
#define XP_BYTES   13778944
#define WT_BYTES   589824
#define WS_NEEDED  14377984

__device__ __forceinline__ unsigned short f2bf(float f) {
    unsigned int u = __float_as_uint(f);
    u = (u + 0x7fffu + ((u >> 16) & 1u)) >> 16;   // RNE
    return (unsigned short)u;
}

__device__ __forceinline__ void gl_lds16(const unsigned short* g, unsigned short* l) {
    __builtin_amdgcn_global_load_lds(
        (const __attribute__((address_space(1))) unsigned int*)g,
        (__attribute__((address_space(3))) unsigned int*)l, 16, 0, 0);
}

// ================= fused aux kernel =================
// blocks [0,288)      : weight transform (4 elems/thread)
// blocks [288,576)    : Wcnt (1 wave per j, 4 j per block)
// blocks [576,2624)   : Xcnt (per (b,ci) block, atomicAdd)
// blocks [2624,4192)  : x transpose+pad+bf16
__global__ __launch_bounds__(256) void k_aux(
    const float* __restrict__ x, const float* __restrict__ w,
    unsigned short* __restrict__ Wt, unsigned short* __restrict__ xp,
    float* __restrict__ Wcnt, float* __restrict__ Xcnt)
{
    __shared__ float T[64][65];
    const int blk = blockIdx.x;
    const int tid = threadIdx.x;

    if (blk < 288) {
        // ---- weight transform: w[co][ci][kh][kw] -> Wt[koff][co][ci] bf16 ----
        int base = (blk * 256 + tid) * 4;
        float4 v = *(const float4*)(w + base);
        #pragma unroll
        for (int j = 0; j < 4; ++j) {
            int e = base + j;
            int co = e / 1152;
            int r  = e - co * 1152;
            int ci = r / 9;
            int koff = r - ci * 9;
            Wt[(koff * 256 + co) * 128 + ci] = f2bf(((const float*)&v)[j]);
        }
    } else if (blk < 576) {
        // ---- Wcnt[j] = sum_co (w[co][j] != 0) ----
        int lane = tid & 63;
        int j = (blk - 288) * 4 + (tid >> 6);
        float c = 0.f;
        for (int co = lane; co < 256; co += 64)
            c += (w[(size_t)co * 1152 + j] != 0.0f) ? 1.f : 0.f;
        #pragma unroll
        for (int s = 32; s > 0; s >>= 1) c += __shfl_down(c, s, 64);
        if (lane == 0) Wcnt[j] = c;
    } else if (blk < 2624) {
        // ---- Xcnt: per (b,ci) nonzero counts in each koff's valid region ----
        int bc = blk - 576;                       // b*128 + ci
        int ci = bc & 127;
        const float* xpk = x + (size_t)bc * SP_;
        float cnt[9];
        #pragma unroll
        for (int k = 0; k < 9; ++k) cnt[k] = 0.f;
        for (int e = tid; e < SP_; e += 256) {
            float v = xpk[e];
            if (v != 0.f) {
                int h = e / 56, w_ = e - h * 56;
                float r0 = (h <= 54) ? 1.f : 0.f;
                float r2 = (h >= 1) ? 1.f : 0.f;
                float c0 = (w_ <= 54) ? 1.f : 0.f;
                float c2 = (w_ >= 1) ? 1.f : 0.f;
                cnt[0] += r0 * c0; cnt[1] += r0; cnt[2] += r0 * c2;
                cnt[3] += c0;      cnt[4] += 1.f; cnt[5] += c2;
                cnt[6] += r2 * c0; cnt[7] += r2; cnt[8] += r2 * c2;
            }
        }
        #pragma unroll
        for (int k = 0; k < 9; ++k) {
            #pragma unroll
            for (int s = 32; s > 0; s >>= 1) cnt[k] += __shfl_down(cnt[k], s, 64);
        }
        if ((tid & 63) == 0) {
            #pragma unroll
            for (int k = 0; k < 9; ++k)
                atomicAdd(&Xcnt[ci * 9 + k], cnt[k]);
        }
    } else {
        // ---- x[b][ci][sp] f32 -> xp[b][ih][iw][ci] bf16 (transpose via LDS) ----
        int i = blk - 2624;
        int sp0 = (i % 49) * 64;
        int rest = i / 49;
        int ci0 = (rest & 1) * 64;
        int b = rest >> 1;
        const float* xb = x + ((size_t)(b * 128 + ci0)) * SP_ + sp0;
        #pragma unroll
        for (int r = 0; r < 16; ++r) {
            const int ci_l = (tid >> 6) * 16 + r;
            const int sp_l = tid & 63;
            T[sp_l][ci_l] = xb[(size_t)ci_l * SP_ + sp_l];
        }
        __syncthreads();
        #pragma unroll
        for (int r = 0; r < 4; ++r) {
            const int sp_l = (tid >> 4) * 4 + r;
            const int cc   = (tid & 15) * 4;
            const int sp = sp0 + sp_l;
            const int oh = sp / 56, ow = sp - oh * 56;
            ushort4v v;
            #pragma unroll
            for (int j = 0; j < 4; ++j) v[j] = f2bf(T[sp_l][cc + j]);
            *(ushort4v*)&xp[(((size_t)b * 58 + oh + 1) * 58 + (ow + 1)) * 128 + ci0 + cc] = v;
        }
    }
}

// ---- final sparsity scalar ----
__global__ void k_spars(const float* __restrict__ Wcnt, const float* __restrict__ Xcnt,
                        float* __restrict__ out_scalar) {
    __shared__ double red[256];
    int t = threadIdx.x;
    double s = 0.0;
    for (int j = t; j < 1152; j += 256)
        s += (double)Wcnt[j] * (double)Xcnt[j];
    red[t] = s; __syncthreads();
    for (int k = 128; k > 0; k >>= 1) {
        if (t < k) red[t] += red[t + k];
        __syncthreads();
    }
    if (t == 0) {
        const double ne = 14797504512.0;
        out_scalar[0] = (float)((ne - red[0]) / ne);
    }
}

// ---- main conv: 128x128 tile, BK=64, ring-2 LDS, counted-vmcnt pipeline (T4) ----
__global__ __launch_bounds__(256) void k_conv2(
    const unsigned short* __restrict__ xp, const unsigned short* __restrict__ Wt,
    const float* __restrict__ bias, float* __restrict__ out)
{
    __shared__ __attribute__((aligned(16))) unsigned short Alds[2 * 8192]; // 32 KB
    __shared__ __attribute__((aligned(16))) unsigned short Blds[2 * 8192]; // 32 KB

    const int tid  = threadIdx.x;
    const int lane = tid & 63;
    const int w    = tid >> 6;
    const int wm   = w >> 1, wn = w & 1;

    const int n0  = blockIdx.x * 128;
    const int co0 = blockIdx.y * 128;

    // staging maps: chunk g=(w*4+q)*64+lane -> row=g>>3, phys p=g&7,
    // logical chunk c = p ^ (row&7)  (rule-21 involution, 0 conflicts verified)
    int aoff[4], boff[4];
    #pragma unroll
    for (int q = 0; q < 4; ++q) {
        int g   = (w * 4 + q) * 64 + lane;
        int row = g >> 3;
        int c   = (g & 7) ^ (row & 7);
        aoff[q] = (co0 + row) * 128 + c * 8;
        int n  = n0 + row;
        int b  = n / SP_;
        int sp = n - b * SP_;
        int oh = sp / 56, ow = sp - oh * 56;
        boff[q] = ((b * 58 + oh + 1) * 58 + (ow + 1)) * 128 + c * 8;
    }

    f32x4 acc[4][4] = {};
    const int l15 = lane & 15;
    const int pc0 = (lane >> 4) ^ (lane & 7);
    const int pc1 = ((lane >> 4) + 4) ^ (lane & 7);

    // stage half [qlo,qlo+2) of step t into buffer buf: 4 vmem instructions
    auto stage2 = [&](int t, int buf, int qlo) {
        int koff = t >> 1, half = t & 1;
        int kd   = koff / 3;
        int dh   = kd - 1, dw = koff - kd * 3 - 1;
        int ash  = koff * 32768 + half * 64;
        int bsh  = (dh * 58 + dw) * 128 + half * 64;
        #pragma unroll
        for (int q = qlo; q < qlo + 2; ++q) {
            gl_lds16(Wt + ash + aoff[q], &Alds[buf * 8192 + (w * 4 + q) * 512]);
            gl_lds16(xp + bsh + boff[q], &Blds[buf * 8192 + (w * 4 + q) * 512]);
        }
    };

    stage2(0, 0, 0); stage2(0, 0, 2);           // step 0: 8 loads in flight

    #pragma unroll 1
    for (int t = 0; t < 18; ++t) {
        const int cur = t & 1;
        // issue next step's half0 into buf^1 (its last reader was step t-1,
        // whose end barrier all waves have passed), then drain ONLY step t's 8.
        if (t < 17) {
            stage2(t + 1, cur ^ 1, 0);                       // +4 -> 12 in flight
            asm volatile("s_waitcnt vmcnt(4)" ::: "memory"); // drain t's 8, keep 4
        } else {
            asm volatile("s_waitcnt vmcnt(0)" ::: "memory");
        }
        asm volatile("s_barrier" ::: "memory");              // all waves drained t's

        const unsigned short* Abase = Alds + cur * 8192 + (wm * 64 + l15) * 64;
        const unsigned short* Bbase = Blds + cur * 8192 + (wn * 64 + l15) * 64;

        bf16x8 a0[4], b0[4];
        #pragma unroll
        for (int m = 0; m < 4; ++m) a0[m] = *(const bf16x8*)(Abase + m * 1024 + pc0 * 8);
        #pragma unroll
        for (int n = 0; n < 4; ++n) b0[n] = *(const bf16x8*)(Bbase + n * 1024 + pc0 * 8);
        if (t < 17) stage2(t + 1, cur ^ 1, 2);               // next's half1: 8 in flight
        #pragma unroll
        for (int m = 0; m < 4; ++m)
            #pragma unroll
            for (int n = 0; n < 4; ++n)
                acc[m][n] = __builtin_amdgcn_mfma_f32_16x16x32_bf16(a0[m], b0[n], acc[m][n], 0, 0, 0);

        bf16x8 a1[4], b1[4];
        #pragma unroll
        for (int m = 0; m < 4; ++m) a1[m] = *(const bf16x8*)(Abase + m * 1024 + pc1 * 8);
        #pragma unroll
        for (int n = 0; n < 4; ++n) b1[n] = *(const bf16x8*)(Bbase + n * 1024 + pc1 * 8);
        #pragma unroll
        for (int m = 0; m < 4; ++m)
            #pragma unroll
            for (int n = 0; n < 4; ++n)
                acc[m][n] = __builtin_amdgcn_mfma_f32_16x16x32_bf16(a1[m], b1[n], acc[m][n], 0, 0, 0);

        asm volatile("s_barrier" ::: "memory");              // cur free for overwrite
    }

    // epilogue: D col(n)=lane&15, row(co)=(lane>>4)*4+r
    const int rb = (lane >> 4) * 4;
    #pragma unroll
    for (int nf = 0; nf < 4; ++nf) {
        int n  = n0 + wn * 64 + nf * 16 + l15;
        int b  = n / SP_;
        int sp = n - b * SP_;
        float* op = out + (size_t)b * CO_ * SP_ + sp;
        #pragma unroll
        for (int m = 0; m < 4; ++m) {
            int co = co0 + wm * 64 + m * 16 + rb;
            #pragma unroll
            for (int r = 0; r < 4; ++r)
                op[(size_t)(co + r) * SP_] = acc[m][nf][r] + bias[co + r];
        }
    }
}

// ================= fallback path (ws too small): R1 kernels =================
__global__ void k_wt(const float* __restrict__ w, unsigned short* __restrict__ Wt) {
    int e = blockIdx.x * 256 + threadIdx.x;
    float v = w[e];
    int co = e / 1152;
    int r  = e - co * 1152;
    int ci = r / 9;
    int koff = r - ci * 9;
    Wt[(koff * 256 + co) * 128 + ci] = f2bf(v);
}

__global__ void k_wcnt(const float* __restrict__ w, float* __restrict__ Wcnt) {
    int j = blockIdx.x;
    int lane = threadIdx.x;
    float c = 0.f;
    for (int co = lane; co < 256; co += 64)
        c += (w[(size_t)co * 1152 + j] != 0.0f) ? 1.f : 0.f;
    #pragma unroll
    for (int s = 32; s > 0; s >>= 1) c += __shfl_down(c, s, 64);
    if (lane == 0) Wcnt[j] = c;
}

__global__ void k_xcnt(const float* __restrict__ x, float* __restrict__ Xcnt) {
    int blk = blockIdx.x;
    int ci = blk & 127;
    const float* xpk = x + (size_t)blk * SP_;
    int tid = threadIdx.x;
    float cnt[9];
    #pragma unroll
    for (int k = 0; k < 9; ++k) cnt[k] = 0.f;
    for (int e = tid; e < SP_; e += 256) {
        float v = xpk[e];
        if (v != 0.f) {
            int h = e / 56, w_ = e - h * 56;
            float r0 = (h <= 54) ? 1.f : 0.f;
            float r2 = (h >= 1) ? 1.f : 0.f;
            float c0 = (w_ <= 54) ? 1.f : 0.f;
            float c2 = (w_ >= 1) ? 1.f : 0.f;
            cnt[0] += r0 * c0; cnt[1] += r0; cnt[2] += r0 * c2;
            cnt[3] += c0;      cnt[4] += 1.f; cnt[5] += c2;
            cnt[6] += r2 * c0; cnt[7] += r2; cnt[8] += r2 * c2;
        }
    }
    #pragma unroll
    for (int k = 0; k < 9; ++k) {
        #pragma unroll
        for (int s = 32; s > 0; s >>= 1) cnt[k] += __shfl_down(cnt[k], s, 64);
    }
    if ((tid & 63) == 0) {
        #pragma unroll
        for (int k = 0; k < 9; ++k)
            atomicAdd(&Xcnt[ci * 9 + k], cnt[k]);
    }
}

__global__ __launch_bounds__(256) void k_conv(
    const float* __restrict__ x, const unsigned short* __restrict__ Wt,
    const float* __restrict__ bias, float* __restrict__ out)
{
    __shared__ __attribute__((aligned(16))) unsigned short AldsF[64][40];
    __shared__ __attribute__((aligned(16))) unsigned short BldsF[64][40];

    const int tid  = threadIdx.x;
    const int lane = tid & 63;
    const int wid  = tid >> 6;
    const int wm   = wid >> 1, wn = wid & 1;

    const int n0  = blockIdx.x * 64;
    const int b   = blockIdx.x / 49;
    const int sp0 = n0 - b * SP_;
    const int co0 = blockIdx.y * 64;

    const int a_co = tid >> 2;
    const int a_ci = (tid & 3) * 8;
    const int b_n  = tid & 63;
    const int b_k0 = (tid >> 6) * 8;

    const int sp = sp0 + b_n;
    const int oh = sp / 56, ow = sp - oh * 56;

    f32x4 acc[2][2] = {};
    const float* xb_base = x + (size_t)b * CIN_ * SP_;

    for (int koff = 0; koff < 9; ++koff) {
        const int dh = koff / 3 - 1, dw = koff - (koff / 3) * 3 - 1;
        const int ih = oh + dh, iw = ow + dw;
        const bool valid = ((unsigned)ih < 56u) && ((unsigned)iw < 56u);
        const float* xb = xb_base + sp + dh * 56 + dw;
        const unsigned short* wp = Wt + ((size_t)(koff * 256 + co0 + a_co)) * 128 + a_ci;

        for (int ci0 = 0; ci0 < 128; ci0 += 32) {
            uint4v av = *(const uint4v*)(wp + ci0);
            *(uint4v*)&AldsF[a_co][a_ci] = av;
            ushort8 bv;
            #pragma unroll
            for (int j = 0; j < 8; ++j) {
                int ci = ci0 + b_k0 + j;
                float v = 0.f;
                if (valid) v = xb[(size_t)ci * SP_];
                bv[j] = f2bf(v);
            }
            *(ushort8*)&BldsF[b_n][b_k0] = bv;
            __syncthreads();

            const int row = lane & 15;
            const int kq  = (lane >> 4) * 8;
            bf16x8 a0 = *(const bf16x8*)&AldsF[wm * 32 + row][kq];
            bf16x8 a1 = *(const bf16x8*)&AldsF[wm * 32 + 16 + row][kq];
            bf16x8 bb0 = *(const bf16x8*)&BldsF[wn * 32 + row][kq];
            bf16x8 bb1 = *(const bf16x8*)&BldsF[wn * 32 + 16 + row][kq];
            acc[0][0] = __builtin_amdgcn_mfma_f32_16x16x32_bf16(a0, bb0, acc[0][0], 0, 0, 0);
            acc[0][1] = __builtin_amdgcn_mfma_f32_16x16x32_bf16(a0, bb1, acc[0][1], 0, 0, 0);
            acc[1][0] = __builtin_amdgcn_mfma_f32_16x16x32_bf16(a1, bb0, acc[1][0], 0, 0, 0);
            acc[1][1] = __builtin_amdgcn_mfma_f32_16x16x32_bf16(a1, bb1, acc[1][1], 0, 0, 0);
            __syncthreads();
        }
    }

    const int col = lane & 15;
    const int rb  = (lane >> 4) * 4;
    #pragma unroll
    for (int f = 0; f < 2; ++f) {
        #pragma unroll
        for (int g = 0; g < 2; ++g) {
            int spc = sp0 + wn * 32 + g * 16 + col;
            #pragma unroll
            for (int r = 0; r < 4; ++r) {
                int co = co0 + wm * 32 + f * 16 + rb + r;
                out[((size_t)(b * CO_ + co)) * SP_ + spc] = acc[f][g][r] + bias[co];
            }
        }
    }
}

extern "C" void kernel_launch(void* const* d_in, const int* in_sizes, int n_in,
                              void* d_out, int out_size, void* d_ws, size_t ws_size,
                              hipStream_t stream) {
    const float* x    = (const float*)d_in[0];
    const float* w    = (const float*)d_in[1];
    const float* bias = (const float*)d_in[2];
    float* out = (float*)d_out;

    if (ws_size >= (size_t)WS_NEEDED) {
        unsigned short* xp = (unsigned short*)d_ws;
        unsigned short* Wt = (unsigned short*)((char*)d_ws + XP_BYTES);
        float* Wcnt = (float*)((char*)d_ws + XP_BYTES + WT_BYTES);
        float* Xcnt = Wcnt + 1152;

        hipMemsetAsync((void*)xp, 0, XP_BYTES, stream);
        hipMemsetAsync((void*)Xcnt, 0, 1152 * sizeof(float), stream);
        hipLaunchKernelGGL(k_aux,   dim3(4192),    dim3(256), 0, stream,
                           x, w, Wt, xp, Wcnt, Xcnt);
        hipLaunchKernelGGL(k_conv2, dim3(392, 2),  dim3(256), 0, stream, xp, Wt, bias, out);
        hipLaunchKernelGGL(k_spars, dim3(1),       dim3(256), 0, stream, Wcnt, Xcnt,
                           out + 12845056);
    } else {
        unsigned short* Wt = (unsigned short*)d_ws;
        float* Wcnt = (float*)((char*)d_ws + WT_BYTES);
        float* Xcnt = Wcnt + 1152;

        hipMemsetAsync((void*)Xcnt, 0, 1152 * sizeof(float), stream);
        hipLaunchKernelGGL(k_wt,    dim3(1152),    dim3(256), 0, stream, w, Wt);
        hipLaunchKernelGGL(k_wcnt,  dim3(1152),    dim3(64),  0, stream, w, Wcnt);
        hipLaunchKernelGGL(k_xcnt,  dim3(2048),    dim3(256), 0, stream, x, Xcnt);
        hipLaunchKernelGGL(k_conv,  dim3(784, 4),  dim3(256), 0, stream, x, Wt, bias, out);
        hipLaunchKernelGGL(k_spars, dim3(1),       dim3(256), 0, stream, Wcnt, Xcnt,
                           out + 12845056);
    }
}